// Round 5
// baseline (495.279 us; speedup 1.0000x reference)
//
#include <hip/hip_runtime.h>
#include <hip/hip_cooperative_groups.h>

namespace cg = cooperative_groups;

#define NN 5200   // nodes
#define NI 5200   // incidences
#define NH 1000   // hyperedges
#define ND 4096   // feature dim
#define SLOPE 0.01f
#define INV_SLOPE 100.0f
#define EBK 64    // max nodes per hyperedge bucket (mean 5.2, Poisson max ~18)
#define NBK 16    // max edges per node bucket (mean 1.0, max ~8)
#define GRID 1024 // cooperative grid: 4 blocks/CU x 256 CUs

__global__ void __launch_bounds__(256, 4) fused_k(
        const float* __restrict__ feat, const int* __restrict__ hidx,
        const float* __restrict__ hw, const float* __restrict__ eww,
        const float* __restrict__ bias, float* __restrict__ nout,
        float* __restrict__ eout, int* __restrict__ ecnt, int* __restrict__ ncnt,
        float* __restrict__ Bsum, float* __restrict__ Dsum,
        int* __restrict__ ebuk, int* __restrict__ nbuk) {
    cg::grid_group grid = cg::this_grid();
    const int tid = blockIdx.x * 256 + threadIdx.x;
    const int nthr = GRID * 256;

    // phase 0: zero counters/sums (ecnt,ncnt,Bsum,Dsum are contiguous)
    for (int i = tid; i < 2 * (NH + NN); i += nthr) ecnt[i] = 0;
    grid.sync();

    // phase 1: build buckets + degree sums
    if (tid < NI) {
        int n = hidx[tid];        // node_idx
        int h = hidx[NI + tid];   // edge_idx
        int p = atomicAdd(&ncnt[n], 1);
        if (p < NBK) nbuk[n * NBK + p] = h;
        int q = atomicAdd(&ecnt[h], 1);
        if (q < EBK) ebuk[h * EBK + q] = n;
        atomicAdd(&Dsum[n], hw[h]);    // D[n] = sum hw[edge_idx]
        atomicAdd(&Bsum[h], eww[n]);   // B[h] = sum EW_weight[node_idx]
    }
    grid.sync();

    // phase 2: edge_out[h] = relu(Binv * sum feat[node])
    for (int task = blockIdx.x; task < NH * 4; task += GRID) {
        int h = task >> 2;
        int col = ((task & 3) << 8) + threadIdx.x;   // float4 index 0..1023
        int cnt = ecnt[h];
        if (cnt > EBK) cnt = EBK;
        float B = Bsum[h];
        float binv = (B == 0.f) ? 0.f : 1.f / B;
        float4 acc = make_float4(0.f, 0.f, 0.f, 0.f);
        for (int j = 0; j < cnt; ++j) {
            int nid = ebuk[h * EBK + j];
            float4 v = ((const float4*)(feat + (size_t)nid * ND))[col];
            acc.x += v.x; acc.y += v.y; acc.z += v.z; acc.w += v.w;
        }
        float4 r;
        r.x = binv * acc.x; r.y = binv * acc.y;
        r.z = binv * acc.z; r.w = binv * acc.w;
        r.x = r.x >= 0.f ? r.x : SLOPE * r.x;
        r.y = r.y >= 0.f ? r.y : SLOPE * r.y;
        r.z = r.z >= 0.f ? r.z : SLOPE * r.z;
        r.w = r.w >= 0.f ? r.w : SLOPE * r.w;
        ((float4*)(eout + (size_t)h * ND))[col] = r;
    }
    grid.sync();

    // phase 3: node_out[n] = relu(Dinv * sum invrelu(eout[h]) + bias)
    for (int task = blockIdx.x; task < NN * 4; task += GRID) {
        int n = task >> 2;
        int col = ((task & 3) << 8) + threadIdx.x;
        int cnt = ncnt[n];
        if (cnt > NBK) cnt = NBK;
        float D = Dsum[n];
        float dinv = (D == 0.f) ? 0.f : 1.f / D;
        float4 acc = make_float4(0.f, 0.f, 0.f, 0.f);
        for (int j = 0; j < cnt; ++j) {
            int hid = nbuk[n * NBK + j];
            float4 v = ((const float4*)(eout + (size_t)hid * ND))[col];
            v.x = v.x >= 0.f ? v.x : INV_SLOPE * v.x;   // invert leaky-relu
            v.y = v.y >= 0.f ? v.y : INV_SLOPE * v.y;
            v.z = v.z >= 0.f ? v.z : INV_SLOPE * v.z;
            v.w = v.w >= 0.f ? v.w : INV_SLOPE * v.w;
            acc.x += v.x; acc.y += v.y; acc.z += v.z; acc.w += v.w;
        }
        float4 b = ((const float4*)bias)[col];
        float4 v;
        v.x = dinv * acc.x + b.x; v.y = dinv * acc.y + b.y;
        v.z = dinv * acc.z + b.z; v.w = dinv * acc.w + b.w;
        v.x = v.x >= 0.f ? v.x : SLOPE * v.x;
        v.y = v.y >= 0.f ? v.y : SLOPE * v.y;
        v.z = v.z >= 0.f ? v.z : SLOPE * v.z;
        v.w = v.w >= 0.f ? v.w : SLOPE * v.w;
        ((float4*)(nout + (size_t)n * ND))[col] = v;
    }
}

extern "C" void kernel_launch(void* const* d_in, const int* in_sizes, int n_in,
                              void* d_out, int out_size, void* d_ws, size_t ws_size,
                              hipStream_t stream) {
    const float* feat = (const float*)d_in[0];   // (5200, 4096)
    const int* hidx   = (const int*)d_in[1];     // (2, 5200)
    const float* hw   = (const float*)d_in[3];   // hyperedge_weight (1000,)
    const float* eww  = (const float*)d_in[6];   // EW_weight (5200,)
    const float* bias = (const float*)d_in[7];   // (4096,)

    float* nout = (float*)d_out;                 // node output: NN*ND
    float* eout = nout + (size_t)NN * ND;        // edge output (relu'd): NH*ND

    int* ws     = (int*)d_ws;
    int* ecnt   = ws;                     // [NH] counters, contiguous block below
    int* ncnt   = ecnt + NH;              // [NN]
    float* Bsum = (float*)(ncnt + NN);    // [NH]
    float* Dsum = Bsum + NH;              // [NN] end of zeroed block
    int* ebuk   = (int*)(Dsum + NN);      // [NH*EBK]
    int* nbuk   = ebuk + NH * EBK;        // [NN*NBK]

    void* args[] = {(void*)&feat, (void*)&hidx, (void*)&hw, (void*)&eww,
                    (void*)&bias, (void*)&nout, (void*)&eout, (void*)&ecnt,
                    (void*)&ncnt, (void*)&Bsum, (void*)&Dsum, (void*)&ebuk,
                    (void*)&nbuk};
    (void)hipLaunchCooperativeKernel((const void*)fused_k, dim3(GRID), dim3(256),
                                     args, 0, stream);
}

// Round 6
// 204.080 us; speedup vs baseline: 2.4269x; 2.4269x over previous
//
#include <hip/hip_runtime.h>

#define NN 5200   // nodes
#define NI 5200   // incidences
#define NH 1000   // hyperedges
#define ND 4096   // feature dim
#define SLOPE 0.01f
#define INV_SLOPE 100.0f
#define EBK 64    // max nodes per hyperedge (mean 5.2, binomial tail < 32; 64 = safe)
#define NBK 16    // max edges per node (mean 1.0, tail < 10)

// One block per hyperedge. Scans hidx to find its incidences (L2-broadcast),
// then edge_out[h] = leaky_relu(Binv * sum_n feat[n]).  Block covers the full
// 4096-float row: thread t owns float4 columns {t, t+256, t+512, t+768} -> 4
// independent loads in flight per gather iteration (MLP=4).
__global__ void __launch_bounds__(256) edge_k(const float* __restrict__ feat,
        const int* __restrict__ hidx, const float* __restrict__ eww,
        float* __restrict__ eout) {
    __shared__ int cnt;
    __shared__ float Bs;
    __shared__ int list[EBK];
    const int h = blockIdx.x, t = threadIdx.x;
    if (t == 0) { cnt = 0; Bs = 0.f; }
    __syncthreads();
    for (int i = t; i < NI; i += 256) {
        if (hidx[NI + i] == h) {          // edge_idx row
            int n = hidx[i];              // node_idx row
            int p = atomicAdd(&cnt, 1);
            if (p < EBK) list[p] = n;
            atomicAdd(&Bs, eww[n]);       // B[h] = sum EW_weight[node]
        }
    }
    __syncthreads();
    int c = cnt < EBK ? cnt : EBK;
    float B = Bs;
    float binv = (B == 0.f) ? 0.f : 1.f / B;

    float4 a0 = make_float4(0.f, 0.f, 0.f, 0.f), a1 = a0, a2 = a0, a3 = a0;
    for (int j = 0; j < c; ++j) {
        const float4* row = (const float4*)(feat + (size_t)list[j] * ND);
        float4 v0 = row[t], v1 = row[t + 256], v2 = row[t + 512], v3 = row[t + 768];
        a0.x += v0.x; a0.y += v0.y; a0.z += v0.z; a0.w += v0.w;
        a1.x += v1.x; a1.y += v1.y; a1.z += v1.z; a1.w += v1.w;
        a2.x += v2.x; a2.y += v2.y; a2.z += v2.z; a2.w += v2.w;
        a3.x += v3.x; a3.y += v3.y; a3.z += v3.z; a3.w += v3.w;
    }
    float4* out = (float4*)(eout + (size_t)h * ND);
#define EFIN(ak, idx)                                              \
    {                                                              \
        float4 r;                                                  \
        r.x = binv * ak.x; r.y = binv * ak.y;                      \
        r.z = binv * ak.z; r.w = binv * ak.w;                      \
        r.x = r.x >= 0.f ? r.x : SLOPE * r.x;                      \
        r.y = r.y >= 0.f ? r.y : SLOPE * r.y;                      \
        r.z = r.z >= 0.f ? r.z : SLOPE * r.z;                      \
        r.w = r.w >= 0.f ? r.w : SLOPE * r.w;                      \
        out[idx] = r;                                              \
    }
    EFIN(a0, t) EFIN(a1, t + 256) EFIN(a2, t + 512) EFIN(a3, t + 768)
#undef EFIN
}

// One block per node. Scans hidx for its edges, gathers relu'd edge rows,
// inverts the activation, normalizes, + bias, relu.
__global__ void __launch_bounds__(256) node_k(const float* __restrict__ eout,
        const int* __restrict__ hidx, const float* __restrict__ hw,
        const float* __restrict__ bias, float* __restrict__ nout) {
    __shared__ int cnt;
    __shared__ float Ds;
    __shared__ int list[NBK];
    const int n = blockIdx.x, t = threadIdx.x;
    if (t == 0) { cnt = 0; Ds = 0.f; }
    __syncthreads();
    for (int i = t; i < NI; i += 256) {
        if (hidx[i] == n) {               // node_idx row
            int h = hidx[NI + i];         // edge_idx row
            int p = atomicAdd(&cnt, 1);
            if (p < NBK) list[p] = h;
            atomicAdd(&Ds, hw[h]);        // D[n] = sum hyperedge_weight[edge]
        }
    }
    __syncthreads();
    int c = cnt < NBK ? cnt : NBK;
    float D = Ds;
    float dinv = (D == 0.f) ? 0.f : 1.f / D;

    float4 a0 = make_float4(0.f, 0.f, 0.f, 0.f), a1 = a0, a2 = a0, a3 = a0;
    for (int j = 0; j < c; ++j) {
        const float4* row = (const float4*)(eout + (size_t)list[j] * ND);
        float4 v0 = row[t], v1 = row[t + 256], v2 = row[t + 512], v3 = row[t + 768];
        // invert leaky-relu to recover raw edge_out
        v0.x = v0.x >= 0.f ? v0.x : INV_SLOPE * v0.x;
        v0.y = v0.y >= 0.f ? v0.y : INV_SLOPE * v0.y;
        v0.z = v0.z >= 0.f ? v0.z : INV_SLOPE * v0.z;
        v0.w = v0.w >= 0.f ? v0.w : INV_SLOPE * v0.w;
        v1.x = v1.x >= 0.f ? v1.x : INV_SLOPE * v1.x;
        v1.y = v1.y >= 0.f ? v1.y : INV_SLOPE * v1.y;
        v1.z = v1.z >= 0.f ? v1.z : INV_SLOPE * v1.z;
        v1.w = v1.w >= 0.f ? v1.w : INV_SLOPE * v1.w;
        v2.x = v2.x >= 0.f ? v2.x : INV_SLOPE * v2.x;
        v2.y = v2.y >= 0.f ? v2.y : INV_SLOPE * v2.y;
        v2.z = v2.z >= 0.f ? v2.z : INV_SLOPE * v2.z;
        v2.w = v2.w >= 0.f ? v2.w : INV_SLOPE * v2.w;
        v3.x = v3.x >= 0.f ? v3.x : INV_SLOPE * v3.x;
        v3.y = v3.y >= 0.f ? v3.y : INV_SLOPE * v3.y;
        v3.z = v3.z >= 0.f ? v3.z : INV_SLOPE * v3.z;
        v3.w = v3.w >= 0.f ? v3.w : INV_SLOPE * v3.w;
        a0.x += v0.x; a0.y += v0.y; a0.z += v0.z; a0.w += v0.w;
        a1.x += v1.x; a1.y += v1.y; a1.z += v1.z; a1.w += v1.w;
        a2.x += v2.x; a2.y += v2.y; a2.z += v2.z; a2.w += v2.w;
        a3.x += v3.x; a3.y += v3.y; a3.z += v3.z; a3.w += v3.w;
    }
    const float4* b4 = (const float4*)bias;
    float4* out = (float4*)(nout + (size_t)n * ND);
#define NFIN(ak, idx)                                              \
    {                                                              \
        float4 b = b4[idx];                                        \
        float4 v;                                                  \
        v.x = dinv * ak.x + b.x; v.y = dinv * ak.y + b.y;          \
        v.z = dinv * ak.z + b.z; v.w = dinv * ak.w + b.w;          \
        v.x = v.x >= 0.f ? v.x : SLOPE * v.x;                      \
        v.y = v.y >= 0.f ? v.y : SLOPE * v.y;                      \
        v.z = v.z >= 0.f ? v.z : SLOPE * v.z;                      \
        v.w = v.w >= 0.f ? v.w : SLOPE * v.w;                      \
        out[idx] = v;                                              \
    }
    NFIN(a0, t) NFIN(a1, t + 256) NFIN(a2, t + 512) NFIN(a3, t + 768)
#undef NFIN
}

extern "C" void kernel_launch(void* const* d_in, const int* in_sizes, int n_in,
                              void* d_out, int out_size, void* d_ws, size_t ws_size,
                              hipStream_t stream) {
    const float* feat = (const float*)d_in[0];   // (5200, 4096)
    const int* hidx   = (const int*)d_in[1];     // (2, 5200)
    const float* hw   = (const float*)d_in[3];   // hyperedge_weight (1000,)
    const float* eww  = (const float*)d_in[6];   // EW_weight (5200,)
    const float* bias = (const float*)d_in[7];   // (4096,)

    float* nout = (float*)d_out;                 // node output: NN*ND
    float* eout = nout + (size_t)NN * ND;        // edge output (relu'd): NH*ND

    edge_k<<<NH, 256, 0, stream>>>(feat, hidx, eww, eout);
    node_k<<<NN, 256, 0, stream>>>(eout, hidx, hw, bias, nout);
}

// Round 8
// 193.339 us; speedup vs baseline: 2.5617x; 1.0556x over previous
//
#include <hip/hip_runtime.h>

#define NN 5200   // nodes
#define NI 5200   // incidences
#define NH 1000   // hyperedges
#define ND 4096   // feature dim
#define SLOPE 0.01f
#define INV_SLOPE 100.0f
#define EBK 64    // max nodes per hyperedge (mean 5.2; binomial tail << 64)
#define NBK 16    // max edges per node (mean 1.0; tail << 16)

typedef float v4f __attribute__((ext_vector_type(4)));

// ---- build buckets + degree sums in one pass over incidences ----
__global__ void build_k(const int* __restrict__ hidx, const float* __restrict__ hw,
                        const float* __restrict__ eww,
                        int* __restrict__ ecnt, int* __restrict__ ncnt,
                        float* __restrict__ Bsum, float* __restrict__ Dsum,
                        int* __restrict__ ebuk, int* __restrict__ nbuk) {
    int i = blockIdx.x * blockDim.x + threadIdx.x;
    if (i < NI) {
        int n = hidx[i];        // node_idx
        int h = hidx[NI + i];   // edge_idx
        int q = atomicAdd(&ecnt[h], 1);
        if (q < EBK) ebuk[h * EBK + q] = n;
        int p = atomicAdd(&ncnt[n], 1);
        if (p < NBK) nbuk[n * NBK + p] = h;
        atomicAdd(&Bsum[h], eww[n]);   // B[h] = sum EW_weight[node]
        atomicAdd(&Dsum[n], hw[h]);    // D[n] = sum hyperedge_weight[edge]
    }
}

// ---- one block per hyperedge: eout[h] = relu(Binv * sum feat[node]) ----
// thread t owns float4 cols {t, t+256, t+512, t+768} -> MLP=4.
__global__ void __launch_bounds__(256) edge_k(const float* __restrict__ feat,
        const int* __restrict__ ecnt, const float* __restrict__ Bsum,
        const int* __restrict__ ebuk, float* __restrict__ eout) {
    const int h = blockIdx.x, t = threadIdx.x;
    int c = ecnt[h];
    if (c > EBK) c = EBK;
    float B = Bsum[h];
    float binv = (B == 0.f) ? 0.f : 1.f / B;

    v4f a0 = (v4f)(0.f), a1 = a0, a2 = a0, a3 = a0;
    for (int j = 0; j < c; ++j) {
        const v4f* row = (const v4f*)(feat + (size_t)ebuk[h * EBK + j] * ND);
        v4f v0 = __builtin_nontemporal_load(row + t);
        v4f v1 = __builtin_nontemporal_load(row + t + 256);
        v4f v2 = __builtin_nontemporal_load(row + t + 512);
        v4f v3 = __builtin_nontemporal_load(row + t + 768);
        a0 += v0; a1 += v1; a2 += v2; a3 += v3;
    }
    v4f* out = (v4f*)(eout + (size_t)h * ND);
#define EFIN(ak, idx)                                              \
    {                                                              \
        v4f r = binv * ak;                                         \
        r.x = r.x >= 0.f ? r.x : SLOPE * r.x;                      \
        r.y = r.y >= 0.f ? r.y : SLOPE * r.y;                      \
        r.z = r.z >= 0.f ? r.z : SLOPE * r.z;                      \
        r.w = r.w >= 0.f ? r.w : SLOPE * r.w;                      \
        out[idx] = r;                                              \
    }
    EFIN(a0, t) EFIN(a1, t + 256) EFIN(a2, t + 512) EFIN(a3, t + 768)
#undef EFIN
}

// ---- one block per node: nout[n] = relu(Dinv * sum invrelu(eout[h]) + bias) ----
__global__ void __launch_bounds__(256) node_k(const float* __restrict__ eout,
        const int* __restrict__ ncnt, const float* __restrict__ Dsum,
        const int* __restrict__ nbuk, const float* __restrict__ bias,
        float* __restrict__ nout) {
    const int n = blockIdx.x, t = threadIdx.x;
    int c = ncnt[n];
    if (c > NBK) c = NBK;
    float D = Dsum[n];
    float dinv = (D == 0.f) ? 0.f : 1.f / D;

    v4f a0 = (v4f)(0.f), a1 = a0, a2 = a0, a3 = a0;
#define IREL(vk)                                                   \
    vk.x = vk.x >= 0.f ? vk.x : INV_SLOPE * vk.x;                  \
    vk.y = vk.y >= 0.f ? vk.y : INV_SLOPE * vk.y;                  \
    vk.z = vk.z >= 0.f ? vk.z : INV_SLOPE * vk.z;                  \
    vk.w = vk.w >= 0.f ? vk.w : INV_SLOPE * vk.w;
    for (int j = 0; j < c; ++j) {
        const v4f* row = (const v4f*)(eout + (size_t)nbuk[n * NBK + j] * ND);
        v4f v0 = row[t], v1 = row[t + 256], v2 = row[t + 512], v3 = row[t + 768];
        IREL(v0) IREL(v1) IREL(v2) IREL(v3)
        a0 += v0; a1 += v1; a2 += v2; a3 += v3;
    }
#undef IREL
    const v4f* b4 = (const v4f*)bias;
    v4f* out = (v4f*)(nout + (size_t)n * ND);
#define NFIN(ak, idx)                                              \
    {                                                              \
        v4f v = dinv * ak + b4[idx];                               \
        v.x = v.x >= 0.f ? v.x : SLOPE * v.x;                      \
        v.y = v.y >= 0.f ? v.y : SLOPE * v.y;                      \
        v.z = v.z >= 0.f ? v.z : SLOPE * v.z;                      \
        v.w = v.w >= 0.f ? v.w : SLOPE * v.w;                      \
        __builtin_nontemporal_store(v, out + idx);                 \
    }
    NFIN(a0, t) NFIN(a1, t + 256) NFIN(a2, t + 512) NFIN(a3, t + 768)
#undef NFIN
}

extern "C" void kernel_launch(void* const* d_in, const int* in_sizes, int n_in,
                              void* d_out, int out_size, void* d_ws, size_t ws_size,
                              hipStream_t stream) {
    const float* feat = (const float*)d_in[0];   // (5200, 4096)
    const int* hidx   = (const int*)d_in[1];     // (2, 5200)
    const float* hw   = (const float*)d_in[3];   // hyperedge_weight (1000,)
    const float* eww  = (const float*)d_in[6];   // EW_weight (5200,)
    const float* bias = (const float*)d_in[7];   // (4096,)

    float* nout = (float*)d_out;                 // node output: NN*ND
    float* eout = nout + (size_t)NN * ND;        // edge output (relu'd): NH*ND

    int* ws     = (int*)d_ws;
    int* ecnt   = ws;                     // [NH]  -- zeroed block start
    int* ncnt   = ecnt + NH;              // [NN]
    float* Bsum = (float*)(ncnt + NN);    // [NH]
    float* Dsum = Bsum + NH;              // [NN]  -- zeroed block end
    int* ebuk   = (int*)(Dsum + NN);      // [NH*EBK]
    int* nbuk   = ebuk + NH * EBK;        // [NN*NBK]

    (void)hipMemsetAsync(ecnt, 0, (size_t)2 * (NH + NN) * sizeof(int), stream);
    build_k<<<(NI + 255) / 256, 256, 0, stream>>>(hidx, hw, eww, ecnt, ncnt,
                                                  Bsum, Dsum, ebuk, nbuk);
    edge_k<<<NH, 256, 0, stream>>>(feat, ecnt, Bsum, ebuk, eout);
    node_k<<<NN, 256, 0, stream>>>(eout, ncnt, Dsum, nbuk, bias, nout);
}